// Round 3
// baseline (78.031 us; speedup 1.0000x reference)
//
#include <hip/hip_runtime.h>
#include <math.h>

// MultiMarginRankingLoss: out = -(1-0.5)*rank_term + 0.5*bce
// rank_term = mean_q [ sum_{p,j} relu(pred[q,p]-pred[q,j]) * nonrel[q,p] * rel[q,j] / NP ]
// bce       = mean_{q,p} [ max(x,0) - x*rel + log1p(exp(-|x|)) ]

constexpr int NQ = 128;
constexpr int NP = 1024;
constexpr int BLK = 1024;   // one thread per p, one block per q-row

__global__ __launch_bounds__(BLK)
void mmrl_main_kernel(const float* __restrict__ pred,
                      const int* __restrict__ y,
                      float* __restrict__ ws) {
    __shared__ float sp[NP];    // pred row
    __shared__ float syf[NP];   // relevance mask (y==1)
    __shared__ float red_r[BLK / 64];
    __shared__ float red_b[BLK / 64];

    const int q = blockIdx.x;
    const int tid = threadIdx.x;

    // Stage row into LDS (tid < NP always since BLK == NP)
    sp[tid] = pred[q * NP + tid];
    syf[tid] = (y[q * NP + tid] == 1) ? 1.0f : 0.0f;
    __syncthreads();

    const float x = sp[tid];
    const float yf = syf[tid];

    // BCE contribution (numerically stable BCEWithLogits)
    float bce = fmaxf(x, 0.0f) - x * yf + log1pf(expf(-fabsf(x)));

    // Rank contribution: this thread's p vs all relevant j.
    // sp[j]/syf[j] are wave-uniform addresses -> LDS broadcast, conflict-free.
    float rank = 0.0f;
    #pragma unroll 8
    for (int j = 0; j < NP; ++j) {
        rank += fmaxf(x - sp[j], 0.0f) * syf[j];
    }
    rank *= (1.0f - yf);   // only non-relevant p contribute

    // Wave (64-lane) shuffle reduction
    #pragma unroll
    for (int off = 32; off > 0; off >>= 1) {
        rank += __shfl_down(rank, off, 64);
        bce  += __shfl_down(bce,  off, 64);
    }
    const int wave = tid >> 6;
    const int lane = tid & 63;
    if (lane == 0) { red_r[wave] = rank; red_b[wave] = bce; }
    __syncthreads();

    if (tid == 0) {
        float r = 0.0f, b = 0.0f;
        #pragma unroll
        for (int w = 0; w < BLK / 64; ++w) { r += red_r[w]; b += red_b[w]; }
        atomicAdd(&ws[0], r);
        atomicAdd(&ws[1], b);
    }
}

__global__ void mmrl_finalize_kernel(const float* __restrict__ ws,
                                     float* __restrict__ out) {
    const float scale = 1.0f / (float)(NQ * NP);
    const float rank_term = ws[0] * scale;  // sum/(NP) per q, then /NQ
    const float bce = ws[1] * scale;
    out[0] = -0.5f * rank_term + 0.5f * bce;
}

extern "C" void kernel_launch(void* const* d_in, const int* in_sizes, int n_in,
                              void* d_out, int out_size, void* d_ws, size_t ws_size,
                              hipStream_t stream) {
    const float* pred = (const float*)d_in[0];
    const int*   y    = (const int*)d_in[1];
    float* ws  = (float*)d_ws;
    float* out = (float*)d_out;

    // ws is re-poisoned to 0xAA before every timed launch -- zero it each call.
    hipMemsetAsync(ws, 0, 2 * sizeof(float), stream);

    mmrl_main_kernel<<<NQ, BLK, 0, stream>>>(pred, y, ws);
    mmrl_finalize_kernel<<<1, 1, 0, stream>>>(ws, out);
}

// Round 4
// 66.819 us; speedup vs baseline: 1.1678x; 1.1678x over previous
//
#include <hip/hip_runtime.h>
#include <math.h>

// MultiMarginRankingLoss: out = -0.5*rank_term + 0.5*bce
// rank_term = sum_{q,p,j} relu(pred[q,p]-pred[q,j]) * [y[q,p]!=1] * [y[q,j]==1] / (NQ*NP)
// bce       = mean_{q,p} [ max(x,0) - x*[y==1] + log1p(exp(-|x|)) ]
//
// Main kernel: 4 blocks per q-row (512 blocks x 256 threads, 2 blocks/CU).
// Per block: compact the row's RELEVANT pred values into an LDS list (order
// doesn't matter, sum is commutative), pad to x64 with +1e30 (relu -> 0).
// Rank loop: one per-lane ds_read per 64-j chunk, then v_readlane SGPR
// broadcasts -- no LDS traffic in the hot loop, pure VALU.

constexpr int NQ  = 128;
constexpr int NP  = 1024;
constexpr int BLK = 256;            // threads per block; each owns 1 p
constexpr int SPLIT = NP / BLK;     // 4 blocks per q
constexpr int GRID = NQ * SPLIT;    // 512 blocks

__global__ __launch_bounds__(BLK)
void mmrl_main_kernel(const float* __restrict__ pred,
                      const int* __restrict__ y,
                      float* __restrict__ partial_r,
                      float* __restrict__ partial_b) {
    __shared__ float sj_list[NP + 64];   // compacted relevant pred values + pad
    __shared__ int   s_cnt;
    __shared__ float red_r[BLK / 64];
    __shared__ float red_b[BLK / 64];

    const int bid = blockIdx.x;
    const int q   = bid >> 2;            // bid / SPLIT
    const int sub = bid & (SPLIT - 1);
    const int tid = threadIdx.x;
    const int lane = tid & 63;

    if (tid == 0) s_cnt = 0;
    __syncthreads();

    // --- Stage + compact: 256 threads x 4 elements cover the full row ---
    const float4 p4 = *reinterpret_cast<const float4*>(pred + q * NP + tid * 4);
    const int4   y4 = *reinterpret_cast<const int4*>(y + q * NP + tid * 4);
    float vals[4];
    int c = 0;
    if (y4.x == 1) vals[c++] = p4.x;
    if (y4.y == 1) vals[c++] = p4.y;
    if (y4.z == 1) vals[c++] = p4.z;
    if (y4.w == 1) vals[c++] = p4.w;
    int base = 0;
    if (c > 0) base = atomicAdd(&s_cnt, c);
    for (int k = 0; k < c; ++k) sj_list[base + k] = vals[k];
    __syncthreads();

    const int n    = s_cnt;
    const int npad = (n + 63) & ~63;
    if (tid < npad - n) sj_list[n + tid] = 1e30f;   // relu(x - 1e30) == 0
    __syncthreads();

    // --- This thread's p (sub-range of the row) ---
    const int   pidx = sub * BLK + tid;
    const float x    = pred[q * NP + pidx];
    const int   yv   = y[q * NP + pidx];
    const float yf   = (yv == 1) ? 1.0f : 0.0f;

    // BCE contribution (stable BCEWithLogits)
    float bce = fmaxf(x, 0.0f) - x * yf + log1pf(expf(-fabsf(x)));

    // --- Rank loop: readlane broadcast, 4 accumulators for ILP ---
    float r0 = 0.0f, r1 = 0.0f, r2 = 0.0f, r3 = 0.0f;
    for (int jc = 0; jc < npad; jc += 64) {
        const int sji = __float_as_int(sj_list[jc + lane]);  // stride-1: conflict-free
        #pragma unroll
        for (int l = 0; l < 64; l += 4) {
            r0 += fmaxf(x - __int_as_float(__builtin_amdgcn_readlane(sji, l + 0)), 0.0f);
            r1 += fmaxf(x - __int_as_float(__builtin_amdgcn_readlane(sji, l + 1)), 0.0f);
            r2 += fmaxf(x - __int_as_float(__builtin_amdgcn_readlane(sji, l + 2)), 0.0f);
            r3 += fmaxf(x - __int_as_float(__builtin_amdgcn_readlane(sji, l + 3)), 0.0f);
        }
    }
    float rank = ((r0 + r1) + (r2 + r3)) * (1.0f - yf);  // only non-relevant p count

    // --- Block reduction: wave shuffle -> LDS -> thread 0 ---
    #pragma unroll
    for (int off = 32; off > 0; off >>= 1) {
        rank += __shfl_down(rank, off, 64);
        bce  += __shfl_down(bce,  off, 64);
    }
    const int wave = tid >> 6;
    if (lane == 0) { red_r[wave] = rank; red_b[wave] = bce; }
    __syncthreads();
    if (tid == 0) {
        float r = 0.0f, b = 0.0f;
        #pragma unroll
        for (int w = 0; w < BLK / 64; ++w) { r += red_r[w]; b += red_b[w]; }
        partial_r[bid] = r;                 // no atomics, no memset needed
        partial_b[bid] = b;
    }
}

__global__ __launch_bounds__(GRID)
void mmrl_finalize_kernel(const float* __restrict__ partial_r,
                          const float* __restrict__ partial_b,
                          float* __restrict__ out) {
    __shared__ float red_r[GRID / 64];
    __shared__ float red_b[GRID / 64];
    const int tid = threadIdx.x;
    float r = partial_r[tid];
    float b = partial_b[tid];
    #pragma unroll
    for (int off = 32; off > 0; off >>= 1) {
        r += __shfl_down(r, off, 64);
        b += __shfl_down(b, off, 64);
    }
    const int wave = tid >> 6;
    const int lane = tid & 63;
    if (lane == 0) { red_r[wave] = r; red_b[wave] = b; }
    __syncthreads();
    if (tid == 0) {
        float rs = 0.0f, bs = 0.0f;
        #pragma unroll
        for (int w = 0; w < GRID / 64; ++w) { rs += red_r[w]; bs += red_b[w]; }
        const float scale = 1.0f / (float)(NQ * NP);
        out[0] = -0.5f * (rs * scale) + 0.5f * (bs * scale);
    }
}

extern "C" void kernel_launch(void* const* d_in, const int* in_sizes, int n_in,
                              void* d_out, int out_size, void* d_ws, size_t ws_size,
                              hipStream_t stream) {
    const float* pred = (const float*)d_in[0];
    const int*   y    = (const int*)d_in[1];
    float* partial_r = (float*)d_ws;
    float* partial_b = partial_r + GRID;
    float* out = (float*)d_out;

    mmrl_main_kernel<<<GRID, BLK, 0, stream>>>(pred, y, partial_r, partial_b);
    mmrl_finalize_kernel<<<1, GRID, 0, stream>>>(partial_r, partial_b, out);
}